// Round 1
// baseline (4683.982 us; speedup 1.0000x reference)
//
#include <hip/hip_runtime.h>

#define BB 8
#define IMG 224
#define PP 16
#define DD 768
#define NLAY 12
#define DI 1536
#define DS 16
#define DTR 48
#define NPATCH 196
#define L_SEQ 196
#define M_ROWS 1568   // BB*NPATCH
#define DCONV 4

// ---------------- im2col: x (B,3,224,224) -> Xp (1568 x 768), k=(c,p,q) ----------------
__global__ __launch_bounds__(256) void im2col_k(const float* __restrict__ x, float* __restrict__ Xp) {
    int idx = blockIdx.x * 256 + threadIdx.x;
    if (idx >= M_ROWS * DD) return;
    int k = idx % DD;
    int m = idx / DD;
    int b = m / NPATCH;
    int t = m % NPATCH;
    int i = t / 14, j = t % 14;
    int c = k / 256;
    int pq = k % 256;
    int p = pq / 16, q = pq % 16;
    Xp[idx] = x[(((size_t)b * 3 + c) * IMG + i * 16 + p) * IMG + j * 16 + q];
}

// ---------------- generic tiled fp32 GEMM: C[M,N] = A[M,K(lda)] * Bw[N,K]^T ----------------
// mode 0: store    mode 1: softplus(acc + bias[n])    mode 2: acc + bias[n] + pos[(m%196)*N+n]
// mode 3: atomicAdd (split-K over gridDim.z)
__global__ __launch_bounds__(256) void gemm_k(
    const float* __restrict__ A, int lda,
    const float* __restrict__ Bw,
    float* __restrict__ C,
    int M, int N, int K,
    const float* __restrict__ bias,
    const float* __restrict__ pos,
    int mode)
{
    __shared__ __align__(16) float As[16][68];
    __shared__ __align__(16) float Bs[16][68];
    int tid = threadIdx.x;
    int m0 = blockIdx.y * 64;
    int n0 = blockIdx.x * 64;
    int tx = tid & 15;
    int ty = tid >> 4;
    float acc[4][4] = {};
    int lrow = tid >> 2;          // 0..63
    int lk4  = (tid & 3) << 2;    // 0,4,8,12
    int kPer = K / gridDim.z;
    int kBeg = blockIdx.z * kPer;
    for (int k0 = kBeg; k0 < kBeg + kPer; k0 += 16) {
        {
            int m = m0 + lrow;
            float4 va = make_float4(0.f, 0.f, 0.f, 0.f);
            if (m < M) va = *(const float4*)&A[(size_t)m * lda + k0 + lk4];
            As[lk4 + 0][lrow] = va.x; As[lk4 + 1][lrow] = va.y;
            As[lk4 + 2][lrow] = va.z; As[lk4 + 3][lrow] = va.w;
        }
        {
            int n = n0 + lrow;
            float4 vb = make_float4(0.f, 0.f, 0.f, 0.f);
            if (n < N) vb = *(const float4*)&Bw[(size_t)n * K + k0 + lk4];
            Bs[lk4 + 0][lrow] = vb.x; Bs[lk4 + 1][lrow] = vb.y;
            Bs[lk4 + 2][lrow] = vb.z; Bs[lk4 + 3][lrow] = vb.w;
        }
        __syncthreads();
#pragma unroll
        for (int kk = 0; kk < 16; ++kk) {
            float4 a4 = *(const float4*)&As[kk][ty * 4];
            float4 b4 = *(const float4*)&Bs[kk][tx * 4];
            float av[4] = {a4.x, a4.y, a4.z, a4.w};
            float bv[4] = {b4.x, b4.y, b4.z, b4.w};
#pragma unroll
            for (int i = 0; i < 4; ++i)
#pragma unroll
                for (int j = 0; j < 4; ++j)
                    acc[i][j] += av[i] * bv[j];
        }
        __syncthreads();
    }
#pragma unroll
    for (int i = 0; i < 4; ++i) {
        int m = m0 + ty * 4 + i;
        if (m >= M) continue;
#pragma unroll
        for (int j = 0; j < 4; ++j) {
            int n = n0 + tx * 4 + j;
            if (n >= N) continue;
            float v = acc[i][j];
            if (mode == 1) {
                v += bias[n];
                v = (v > 20.f) ? v : log1pf(__expf(v));
            } else if (mode == 2) {
                v += bias[n] + pos[(size_t)(m % NPATCH) * N + n];
            }
            if (mode == 3) atomicAdd(&C[(size_t)m * N + n], v);
            else           C[(size_t)m * N + n] = v;
        }
    }
}

// ---------------- causal depthwise conv (k=4) + SiLU ----------------
// xz (B,L,3072): first DI cols are the conv input; out xc (B,L,1536)
__global__ __launch_bounds__(256) void conv_k(
    const float* __restrict__ xz, const float* __restrict__ cw,
    const float* __restrict__ cb, float* __restrict__ xc)
{
    int idx = blockIdx.x * 256 + threadIdx.x;
    if (idx >= M_ROWS * DI) return;
    int e = idx % DI;
    int m = idx / DI;          // b*196 + l
    int l = m % L_SEQ;
    float acc = cb[e];
#pragma unroll
    for (int k = 0; k < DCONV; ++k) {
        int ls = l + k - (DCONV - 1);
        if (ls >= 0) acc += cw[e * DCONV + k] * xz[(size_t)(m + k - (DCONV - 1)) * (2 * DI) + e];
    }
    xc[idx] = acc / (1.f + __expf(-acc));   // silu
}

// ---------------- selective scan: one thread per (b, d) channel, 16 states in regs ----------------
__global__ __launch_bounds__(64) void scan_k(
    const float* __restrict__ dt, const float* __restrict__ xc,
    const float* __restrict__ proj, const float* __restrict__ xz,
    const float* __restrict__ A_log, const float* __restrict__ Dp,
    float* __restrict__ y)
{
    int d = blockIdx.x * 64 + threadIdx.x;
    int b = blockIdx.y;
    float Aa[DS];
#pragma unroll
    for (int s = 0; s < DS; ++s) Aa[s] = -__expf(A_log[d * DS + s]);
    float h[DS];
#pragma unroll
    for (int s = 0; s < DS; ++s) h[s] = 0.f;
    float dP = Dp[d];

    float dt0, xv0, zv0, Bv0[DS], Cv0[DS];
    float dt1, xv1, zv1, Bv1[DS], Cv1[DS];

#define LOADI(S, LL) { size_t base = (size_t)b * L_SEQ + (LL); \
    dt##S = dt[base * DI + d]; xv##S = xc[base * DI + d]; zv##S = xz[base * (2 * DI) + DI + d]; \
    const float* pr = proj + base * 80; \
    _Pragma("unroll") for (int s = 0; s < DS; ++s) { Bv##S[s] = pr[DTR + s]; Cv##S[s] = pr[DTR + DS + s]; } }

#define COMPI(S, LL) { float dx = dt##S * xv##S; float accv = 0.f; \
    _Pragma("unroll") for (int s = 0; s < DS; ++s) { \
        h[s] = __expf(dt##S * Aa[s]) * h[s] + dx * Bv##S[s]; accv += h[s] * Cv##S[s]; } \
    float yv = accv + xv##S * dP; \
    float sg = 1.f / (1.f + __expf(-zv##S)); \
    y[((size_t)b * L_SEQ + (LL)) * DI + d] = yv * (zv##S * sg); }

    LOADI(0, 0);
    for (int l = 0; l < L_SEQ; l += 2) {
        LOADI(1, l + 1);
        COMPI(0, l);
        if (l + 2 < L_SEQ) LOADI(0, l + 2);
        COMPI(1, l + 1);
    }
#undef LOADI
#undef COMPI
}

// ---------------- layernorm over D=768 ----------------
__global__ __launch_bounds__(256) void ln_k(const float* __restrict__ h,
    const float* __restrict__ w, const float* __restrict__ bias, float* __restrict__ out)
{
    int row = blockIdx.x;
    int tid = threadIdx.x;
    const float* hr = h + (size_t)row * DD;
    float v0 = hr[tid], v1 = hr[tid + 256], v2 = hr[tid + 512];
    float s = v0 + v1 + v2;
    __shared__ float red[4];
    for (int off = 32; off; off >>= 1) s += __shfl_down(s, off);
    if ((tid & 63) == 0) red[tid >> 6] = s;
    __syncthreads();
    float mu = (red[0] + red[1] + red[2] + red[3]) * (1.f / 768.f);
    __syncthreads();
    float d0 = v0 - mu, d1 = v1 - mu, d2 = v2 - mu;
    float vs = d0 * d0 + d1 * d1 + d2 * d2;
    for (int off = 32; off; off >>= 1) vs += __shfl_down(vs, off);
    if ((tid & 63) == 0) red[tid >> 6] = vs;
    __syncthreads();
    float var = (red[0] + red[1] + red[2] + red[3]) * (1.f / 768.f);
    float rs = rsqrtf(var + 1e-5f);
    out[(size_t)row * DD + tid]       = d0 * rs * w[tid]       + bias[tid];
    out[(size_t)row * DD + tid + 256] = d1 * rs * w[tid + 256] + bias[tid + 256];
    out[(size_t)row * DD + tid + 512] = d2 * rs * w[tid + 512] + bias[tid + 512];
}

__global__ __launch_bounds__(256) void fill0_k(float* __restrict__ p, int n) {
    int i = blockIdx.x * 256 + threadIdx.x;
    if (i < n) p[i] = 0.f;
}

extern "C" void kernel_launch(void* const* d_in, const int* in_sizes, int n_in,
                              void* d_out, int out_size, void* d_ws, size_t ws_size,
                              hipStream_t stream) {
    const float* x        = (const float*)d_in[0];
    const float* patch_w  = (const float*)d_in[1];
    const float* patch_b  = (const float*)d_in[2];
    const float* pos      = (const float*)d_in[3];
    const float* in_proj  = (const float*)d_in[4];
    const float* conv_w   = (const float*)d_in[5];
    const float* conv_b   = (const float*)d_in[6];
    const float* x_proj   = (const float*)d_in[7];
    const float* dt_w     = (const float*)d_in[8];
    const float* dt_b     = (const float*)d_in[9];
    const float* A_log    = (const float*)d_in[10];
    const float* D_param  = (const float*)d_in[11];
    const float* out_w    = (const float*)d_in[12];
    const float* norm_w   = (const float*)d_in[13];
    const float* norm_b   = (const float*)d_in[14];
    float* out = (float*)d_out;

    float* ws    = (float*)d_ws;
    float* Xp    = ws;                      // 1568*768   = 1,204,224
    float* hbuf  = Xp    + 1204224;         // 1568*768   = 1,204,224
    float* xzb   = hbuf  + 1204224;         // 1568*3072  = 4,816,896
    float* xcb   = xzb   + 4816896;         // 1568*1536  = 2,408,448
    float* projb = xcb   + 2408448;         // 1568*80    = 125,440
    float* dtb   = projb + 125440;          // 1568*1536  = 2,408,448
    float* yb    = dtb   + 2408448;         // 1568*1536  = 2,408,448

    // patch embed: im2col + GEMM(+bias+pos)
    im2col_k<<<(M_ROWS * DD + 255) / 256, 256, 0, stream>>>(x, Xp);
    gemm_k<<<dim3(12, 25), 256, 0, stream>>>(Xp, DD, patch_w, hbuf, M_ROWS, DD, DD, patch_b, pos, 2);

    for (int l = 0; l < NLAY; ++l) {
        // in_proj: (1568,768) x (3072,768)^T -> xz
        gemm_k<<<dim3(48, 25), 256, 0, stream>>>(hbuf, DD, in_proj + (size_t)l * 2 * DI * DD, xzb,
                                                 M_ROWS, 2 * DI, DD, nullptr, nullptr, 0);
        // causal conv + silu -> xc
        conv_k<<<(M_ROWS * DI) / 256, 256, 0, stream>>>(xzb, conv_w + (size_t)l * DI * DCONV,
                                                        conv_b + (size_t)l * DI, xcb);
        // x_proj (N=80, skinny): split-K=4 with atomicAdd into zeroed proj
        fill0_k<<<(M_ROWS * 80 + 255) / 256, 256, 0, stream>>>(projb, M_ROWS * 80);
        gemm_k<<<dim3(2, 25, 4), 256, 0, stream>>>(xcb, DI, x_proj + (size_t)l * 80 * DI, projb,
                                                   M_ROWS, 80, DI, nullptr, nullptr, 3);
        // dt_proj: proj[:, :48] x (1536,48)^T + bias -> softplus
        gemm_k<<<dim3(24, 25), 256, 0, stream>>>(projb, 80, dt_w + (size_t)l * DI * DTR, dtb,
                                                 M_ROWS, DI, DTR, dt_b + (size_t)l * DI, nullptr, 1);
        // selective scan + D skip + silu(z) gate
        scan_k<<<dim3(DI / 64, BB), 64, 0, stream>>>(dtb, xcb, projb, xzb,
                                                     A_log + (size_t)l * DI * DS,
                                                     D_param + (size_t)l * DI, yb);
        // out_proj: (1568,1536) x (768,1536)^T -> h (in place, h not needed anymore)
        gemm_k<<<dim3(12, 25), 256, 0, stream>>>(yb, DI, out_w + (size_t)l * DD * DI, hbuf,
                                                 M_ROWS, DD, DI, nullptr, nullptr, 0);
    }

    ln_k<<<M_ROWS, 256, 0, stream>>>(hbuf, norm_w, norm_b, out);
}

// Round 2
// 3433.104 us; speedup vs baseline: 1.3644x; 1.3644x over previous
//
#include <hip/hip_runtime.h>

#define BB 8
#define IMG 224
#define DD 768
#define NLAY 12
#define DI 1536
#define DS 16
#define DTR 48
#define NPATCH 196
#define L_SEQ 196
#define M_ROWS 1568   // BB*NPATCH
#define DCONV 4

typedef _Float16 f16x8 __attribute__((ext_vector_type(8)));
typedef _Float16 f16x4 __attribute__((ext_vector_type(4)));
typedef float f32x4 __attribute__((ext_vector_type(4)));

// ---------------- split fp32 -> (hi,lo) f16 planes, 4 elems/thread ----------------
__global__ __launch_bounds__(256) void split4_k(const float* __restrict__ in,
    _Float16* __restrict__ hi, _Float16* __restrict__ lo, int n4)
{
    int i = blockIdx.x * 256 + threadIdx.x;
    if (i >= n4) return;
    float4 v = ((const float4*)in)[i];
    _Float16 h0 = (_Float16)v.x, h1 = (_Float16)v.y, h2 = (_Float16)v.z, h3 = (_Float16)v.w;
    f16x4 H = {h0, h1, h2, h3};
    f16x4 L = {(_Float16)(v.x - (float)h0), (_Float16)(v.y - (float)h1),
               (_Float16)(v.z - (float)h2), (_Float16)(v.w - (float)h3)};
    ((f16x4*)hi)[i] = H;
    ((f16x4*)lo)[i] = L;
}

// ---------------- im2col with split output: x (B,3,224,224) -> Xp hi/lo (1568 x 768) ----------------
__global__ __launch_bounds__(256) void im2col_k(const float* __restrict__ x,
    _Float16* __restrict__ hi, _Float16* __restrict__ lo)
{
    int idx = blockIdx.x * 256 + threadIdx.x;
    if (idx >= M_ROWS * DD) return;
    int k = idx % DD;
    int m = idx / DD;
    int b = m / NPATCH;
    int t = m % NPATCH;
    int i = t / 14, j = t % 14;
    int c = k / 256;
    int pq = k % 256;
    int p = pq / 16, q = pq % 16;
    float v = x[(((size_t)b * 3 + c) * IMG + i * 16 + p) * IMG + j * 16 + q];
    _Float16 h = (_Float16)v;
    hi[idx] = h;
    lo[idx] = (_Float16)(v - (float)h);
}

// ---------------- f16x3 MFMA GEMM: C[M,N] = (Ah+Al)[M,K] * (Bh+Bl)[N,K]^T (fp32-ish accuracy) ----
// BM=128 BN=64 BK=32, 256 thr = 4 waves (2x2), each wave 64x32 = 4x2 frags of 16x16.
// mode 0: plain store   mode 2: += bias[n] + pos[(m%196)*N+n]
// Chi/Clo non-null: also store f16 hi/lo split of C.
__global__ __launch_bounds__(256) void mgemm_k(
    const _Float16* __restrict__ Ah, const _Float16* __restrict__ Al,
    const _Float16* __restrict__ Bh, const _Float16* __restrict__ Bl,
    float* __restrict__ C, _Float16* __restrict__ Chi, _Float16* __restrict__ Clo,
    int M, int N, int K,
    const float* __restrict__ bias, const float* __restrict__ pos, int mode)
{
    __shared__ _Float16 As[2][128][40];   // [plane][m][k], 40-half row stride (16B-aligned, ~2-way banks)
    __shared__ _Float16 Bs[2][64][40];
    int tid = threadIdx.x;
    int m0 = blockIdx.y * 128, n0 = blockIdx.x * 64;
    int lane = tid & 63;
    int wid = tid >> 6;
    int wM = (wid >> 1) * 64, wN = (wid & 1) * 32;
    int lm = lane & 15, quad = lane >> 4;

    f32x4 acc[4][2] = {};

    // staging map: A: plane=tid>>7, row=tid&127, 32 halfs. B: plane=tid>>7, row=(tid>>1)&63, 16-half seg=tid&1
    int apl = tid >> 7, arow = tid & 127;
    int bpl = tid >> 7, brow = (tid >> 1) & 63, bseg = tid & 1;
    const _Float16* Asrc = apl ? Al : Ah;
    const _Float16* Bsrc = bpl ? Bl : Bh;
    int gm = m0 + arow;
    int gn = n0 + brow;

    for (int k0 = 0; k0 < K; k0 += 32) {
        float4 av0 = make_float4(0.f,0.f,0.f,0.f), av1 = av0, av2 = av0, av3 = av0;
        if (gm < M) {
            const float4* p = (const float4*)&Asrc[(size_t)gm * K + k0];
            av0 = p[0]; av1 = p[1]; av2 = p[2]; av3 = p[3];
        }
        const float4* q = (const float4*)&Bsrc[(size_t)gn * K + k0 + bseg * 16];
        float4 bv0 = q[0], bv1 = q[1];
        *(float4*)&As[apl][arow][0]  = av0;
        *(float4*)&As[apl][arow][8]  = av1;
        *(float4*)&As[apl][arow][16] = av2;
        *(float4*)&As[apl][arow][24] = av3;
        *(float4*)&Bs[bpl][brow][bseg * 16]     = bv0;
        *(float4*)&Bs[bpl][brow][bseg * 16 + 8] = bv1;
        __syncthreads();

        f16x8 a_h[4], a_l[4], b_h[2], b_l[2];
#pragma unroll
        for (int mi = 0; mi < 4; ++mi) {
            a_h[mi] = *(const f16x8*)&As[0][wM + mi * 16 + lm][quad * 8];
            a_l[mi] = *(const f16x8*)&As[1][wM + mi * 16 + lm][quad * 8];
        }
#pragma unroll
        for (int ni = 0; ni < 2; ++ni) {
            b_h[ni] = *(const f16x8*)&Bs[0][wN + ni * 16 + lm][quad * 8];
            b_l[ni] = *(const f16x8*)&Bs[1][wN + ni * 16 + lm][quad * 8];
        }
#pragma unroll
        for (int mi = 0; mi < 4; ++mi)
#pragma unroll
            for (int ni = 0; ni < 2; ++ni) {
                acc[mi][ni] = __builtin_amdgcn_mfma_f32_16x16x32_f16(a_h[mi], b_h[ni], acc[mi][ni], 0, 0, 0);
                acc[mi][ni] = __builtin_amdgcn_mfma_f32_16x16x32_f16(a_h[mi], b_l[ni], acc[mi][ni], 0, 0, 0);
                acc[mi][ni] = __builtin_amdgcn_mfma_f32_16x16x32_f16(a_l[mi], b_h[ni], acc[mi][ni], 0, 0, 0);
            }
        __syncthreads();
    }

#pragma unroll
    for (int mi = 0; mi < 4; ++mi)
#pragma unroll
        for (int ni = 0; ni < 2; ++ni)
#pragma unroll
            for (int r = 0; r < 4; ++r) {
                int row = m0 + wM + mi * 16 + quad * 4 + r;
                if (row >= M) continue;
                int col = n0 + wN + ni * 16 + lm;
                float v = acc[mi][ni][r];
                if (mode == 2) v += bias[col] + pos[(size_t)(row % NPATCH) * N + col];
                size_t idx = (size_t)row * N + col;
                C[idx] = v;
                if (Chi) {
                    _Float16 h = (_Float16)v;
                    Chi[idx] = h;
                    Clo[idx] = (_Float16)(v - (float)h);
                }
            }
}

// ---------------- generic tiled fp32 GEMM (kept for x_proj / dt_proj) ----------------
// mode 1: softplus(acc + bias[n])    mode 3: atomicAdd (split-K over gridDim.z)
__global__ __launch_bounds__(256) void gemm_k(
    const float* __restrict__ A, int lda,
    const float* __restrict__ Bw,
    float* __restrict__ C,
    int M, int N, int K,
    const float* __restrict__ bias,
    int mode)
{
    __shared__ __align__(16) float As[16][68];
    __shared__ __align__(16) float Bs[16][68];
    int tid = threadIdx.x;
    int m0 = blockIdx.y * 64;
    int n0 = blockIdx.x * 64;
    int tx = tid & 15;
    int ty = tid >> 4;
    float acc[4][4] = {};
    int lrow = tid >> 2;
    int lk4  = (tid & 3) << 2;
    int kPer = K / gridDim.z;
    int kBeg = blockIdx.z * kPer;
    for (int k0 = kBeg; k0 < kBeg + kPer; k0 += 16) {
        {
            int m = m0 + lrow;
            float4 va = make_float4(0.f, 0.f, 0.f, 0.f);
            if (m < M) va = *(const float4*)&A[(size_t)m * lda + k0 + lk4];
            As[lk4 + 0][lrow] = va.x; As[lk4 + 1][lrow] = va.y;
            As[lk4 + 2][lrow] = va.z; As[lk4 + 3][lrow] = va.w;
        }
        {
            int n = n0 + lrow;
            float4 vb = make_float4(0.f, 0.f, 0.f, 0.f);
            if (n < N) vb = *(const float4*)&Bw[(size_t)n * K + k0 + lk4];
            Bs[lk4 + 0][lrow] = vb.x; Bs[lk4 + 1][lrow] = vb.y;
            Bs[lk4 + 2][lrow] = vb.z; Bs[lk4 + 3][lrow] = vb.w;
        }
        __syncthreads();
#pragma unroll
        for (int kk = 0; kk < 16; ++kk) {
            float4 a4 = *(const float4*)&As[kk][ty * 4];
            float4 b4 = *(const float4*)&Bs[kk][tx * 4];
            float av[4] = {a4.x, a4.y, a4.z, a4.w};
            float bv[4] = {b4.x, b4.y, b4.z, b4.w};
#pragma unroll
            for (int i = 0; i < 4; ++i)
#pragma unroll
                for (int j = 0; j < 4; ++j)
                    acc[i][j] += av[i] * bv[j];
        }
        __syncthreads();
    }
#pragma unroll
    for (int i = 0; i < 4; ++i) {
        int m = m0 + ty * 4 + i;
        if (m >= M) continue;
#pragma unroll
        for (int j = 0; j < 4; ++j) {
            int n = n0 + tx * 4 + j;
            if (n >= N) continue;
            float v = acc[i][j];
            if (mode == 1) {
                v += bias[n];
                v = (v > 20.f) ? v : log1pf(__expf(v));
            }
            if (mode == 3) atomicAdd(&C[(size_t)m * N + n], v);
            else           C[(size_t)m * N + n] = v;
        }
    }
}

// ---------------- causal depthwise conv (k=4) + SiLU ----------------
__global__ __launch_bounds__(256) void conv_k(
    const float* __restrict__ xz, const float* __restrict__ cw,
    const float* __restrict__ cb, float* __restrict__ xc)
{
    int idx = blockIdx.x * 256 + threadIdx.x;
    if (idx >= M_ROWS * DI) return;
    int e = idx % DI;
    int m = idx / DI;
    int l = m % L_SEQ;
    float acc = cb[e];
#pragma unroll
    for (int k = 0; k < DCONV; ++k) {
        int ls = l + k - (DCONV - 1);
        if (ls >= 0) acc += cw[e * DCONV + k] * xz[(size_t)(m + k - (DCONV - 1)) * (2 * DI) + e];
    }
    xc[idx] = acc / (1.f + __expf(-acc));
}

// ---------------- selective scan: one thread per (b,d); writes y split to f16 hi/lo ----------------
__global__ __launch_bounds__(64) void scan_k(
    const float* __restrict__ dt, const float* __restrict__ xc,
    const float* __restrict__ proj, const float* __restrict__ xz,
    const float* __restrict__ A_log, const float* __restrict__ Dp,
    _Float16* __restrict__ yh, _Float16* __restrict__ yl)
{
    int d = blockIdx.x * 64 + threadIdx.x;
    int b = blockIdx.y;
    float Aa[DS];
#pragma unroll
    for (int s = 0; s < DS; ++s) Aa[s] = -__expf(A_log[d * DS + s]);
    float h[DS];
#pragma unroll
    for (int s = 0; s < DS; ++s) h[s] = 0.f;
    float dP = Dp[d];

    float dt0, xv0, zv0, Bv0[DS], Cv0[DS];
    float dt1, xv1, zv1, Bv1[DS], Cv1[DS];

#define LOADI(S, LL) { size_t base = (size_t)b * L_SEQ + (LL); \
    dt##S = dt[base * DI + d]; xv##S = xc[base * DI + d]; zv##S = xz[base * (2 * DI) + DI + d]; \
    const float* pr = proj + base * 80; \
    _Pragma("unroll") for (int s = 0; s < DS; ++s) { Bv##S[s] = pr[DTR + s]; Cv##S[s] = pr[DTR + DS + s]; } }

#define COMPI(S, LL) { float dx = dt##S * xv##S; float accv = 0.f; \
    _Pragma("unroll") for (int s = 0; s < DS; ++s) { \
        h[s] = __expf(dt##S * Aa[s]) * h[s] + dx * Bv##S[s]; accv += h[s] * Cv##S[s]; } \
    float yv = accv + xv##S * dP; \
    float sg = 1.f / (1.f + __expf(-zv##S)); \
    float vy = yv * (zv##S * sg); \
    size_t oidx = ((size_t)b * L_SEQ + (LL)) * DI + d; \
    _Float16 hh = (_Float16)vy; \
    yh[oidx] = hh; yl[oidx] = (_Float16)(vy - (float)hh); }

    LOADI(0, 0);
    for (int l = 0; l < L_SEQ; l += 2) {
        LOADI(1, l + 1);
        COMPI(0, l);
        if (l + 2 < L_SEQ) LOADI(0, l + 2);
        COMPI(1, l + 1);
    }
#undef LOADI
#undef COMPI
}

// ---------------- layernorm over D=768 ----------------
__global__ __launch_bounds__(256) void ln_k(const float* __restrict__ h,
    const float* __restrict__ w, const float* __restrict__ bias, float* __restrict__ out)
{
    int row = blockIdx.x;
    int tid = threadIdx.x;
    const float* hr = h + (size_t)row * DD;
    float v0 = hr[tid], v1 = hr[tid + 256], v2 = hr[tid + 512];
    float s = v0 + v1 + v2;
    __shared__ float red[4];
    for (int off = 32; off; off >>= 1) s += __shfl_down(s, off);
    if ((tid & 63) == 0) red[tid >> 6] = s;
    __syncthreads();
    float mu = (red[0] + red[1] + red[2] + red[3]) * (1.f / 768.f);
    __syncthreads();
    float d0 = v0 - mu, d1 = v1 - mu, d2 = v2 - mu;
    float vs = d0 * d0 + d1 * d1 + d2 * d2;
    for (int off = 32; off; off >>= 1) vs += __shfl_down(vs, off);
    if ((tid & 63) == 0) red[tid >> 6] = vs;
    __syncthreads();
    float var = (red[0] + red[1] + red[2] + red[3]) * (1.f / 768.f);
    float rs = rsqrtf(var + 1e-5f);
    out[(size_t)row * DD + tid]       = d0 * rs * w[tid]       + bias[tid];
    out[(size_t)row * DD + tid + 256] = d1 * rs * w[tid + 256] + bias[tid + 256];
    out[(size_t)row * DD + tid + 512] = d2 * rs * w[tid + 512] + bias[tid + 512];
}

__global__ __launch_bounds__(256) void fill0_k(float* __restrict__ p, int n) {
    int i = blockIdx.x * 256 + threadIdx.x;
    if (i < n) p[i] = 0.f;
}

extern "C" void kernel_launch(void* const* d_in, const int* in_sizes, int n_in,
                              void* d_out, int out_size, void* d_ws, size_t ws_size,
                              hipStream_t stream) {
    const float* x        = (const float*)d_in[0];
    const float* patch_w  = (const float*)d_in[1];
    const float* patch_b  = (const float*)d_in[2];
    const float* pos      = (const float*)d_in[3];
    const float* in_proj  = (const float*)d_in[4];
    const float* conv_w   = (const float*)d_in[5];
    const float* conv_b   = (const float*)d_in[6];
    const float* x_proj   = (const float*)d_in[7];
    const float* dt_w     = (const float*)d_in[8];
    const float* dt_b     = (const float*)d_in[9];
    const float* A_log    = (const float*)d_in[10];
    const float* D_param  = (const float*)d_in[11];
    const float* out_w    = (const float*)d_in[12];
    const float* norm_w   = (const float*)d_in[13];
    const float* norm_b   = (const float*)d_in[14];
    float* out = (float*)d_out;

    // fp32 workspace
    float* ws    = (float*)d_ws;
    float* hbuf  = ws;                      // 1,204,224
    float* xzb   = hbuf  + 1204224;         // 4,816,896
    float* xcb   = xzb   + 4816896;         // 2,408,448
    float* projb = xcb   + 2408448;         //   125,440
    float* dtb   = projb + 125440;          // 2,408,448
    // f16 split workspace
    _Float16* h16 = (_Float16*)(dtb + 2408448);
    _Float16* hbh = h16;                    // 1,204,224
    _Float16* hbl = hbh + 1204224;          // 1,204,224
    _Float16* yh  = hbl + 1204224;          // 2,408,448 (also holds im2col hi at start)
    _Float16* yl  = yh  + 2408448;          // 2,408,448
    _Float16* pwh = yl  + 2408448;          //   589,824
    _Float16* pwl = pwh + 589824;
    _Float16* wih = pwl + 589824;           // 2,359,296 (per-layer in_proj_w split, reused)
    _Float16* wil = wih + 2359296;
    _Float16* woh = wil + 2359296;          // 1,179,648 (per-layer out_proj_w split, reused)
    _Float16* wol = woh + 1179648;

    // patch embed: split patch_w, im2col-split, MFMA GEMM (+bias+pos, emit hbuf splits)
    split4_k<<<(589824 / 4 + 255) / 256, 256, 0, stream>>>(patch_w, pwh, pwl, 589824 / 4);
    im2col_k<<<(M_ROWS * DD + 255) / 256, 256, 0, stream>>>(x, yh, yl);
    mgemm_k<<<dim3(DD / 64, (M_ROWS + 127) / 128), 256, 0, stream>>>(
        yh, yl, pwh, pwl, hbuf, hbh, hbl, M_ROWS, DD, DD, patch_b, pos, 2);

    for (int l = 0; l < NLAY; ++l) {
        // split this layer's big weights
        split4_k<<<(2359296 / 4 + 255) / 256, 256, 0, stream>>>(
            in_proj + (size_t)l * 2 * DI * DD, wih, wil, 2359296 / 4);
        split4_k<<<(1179648 / 4 + 255) / 256, 256, 0, stream>>>(
            out_w + (size_t)l * DD * DI, woh, wol, 1179648 / 4);
        // in_proj: (1568,768) x (3072,768)^T -> xz (fp32)
        mgemm_k<<<dim3(2 * DI / 64, (M_ROWS + 127) / 128), 256, 0, stream>>>(
            hbh, hbl, wih, wil, xzb, nullptr, nullptr, M_ROWS, 2 * DI, DD, nullptr, nullptr, 0);
        // causal conv + silu -> xc
        conv_k<<<(M_ROWS * DI) / 256, 256, 0, stream>>>(xzb, conv_w + (size_t)l * DI * DCONV,
                                                        conv_b + (size_t)l * DI, xcb);
        // x_proj (N=80 skinny): split-K=4 atomicAdd
        fill0_k<<<(M_ROWS * 80 + 255) / 256, 256, 0, stream>>>(projb, M_ROWS * 80);
        gemm_k<<<dim3(2, 25, 4), 256, 0, stream>>>(xcb, DI, x_proj + (size_t)l * 80 * DI, projb,
                                                   M_ROWS, 80, DI, nullptr, 3);
        // dt_proj: proj[:, :48] x (1536,48)^T + bias -> softplus
        gemm_k<<<dim3(24, 25), 256, 0, stream>>>(projb, 80, dt_w + (size_t)l * DI * DTR, dtb,
                                                 M_ROWS, DI, DTR, dt_b + (size_t)l * DI, 1);
        // selective scan + D skip + silu(z) gate -> y split
        scan_k<<<dim3(DI / 64, BB), 64, 0, stream>>>(dtb, xcb, projb, xzb,
                                                     A_log + (size_t)l * DI * DS,
                                                     D_param + (size_t)l * DI, yh, yl);
        // out_proj: (1568,1536) x (768,1536)^T -> hbuf (+ splits for next layer)
        mgemm_k<<<dim3(DD / 64, (M_ROWS + 127) / 128), 256, 0, stream>>>(
            yh, yl, woh, wol, hbuf, hbh, hbl, M_ROWS, DD, DI, nullptr, nullptr, 0);
    }

    ln_k<<<M_ROWS, 256, 0, stream>>>(hbuf, norm_w, norm_b, out);
}